// Round 12
// baseline (68.879 us; speedup 1.0000x reference)
//
#include <hip/hip_runtime.h>

typedef __attribute__((ext_vector_type(8))) short bf16x8;
typedef __attribute__((ext_vector_type(4))) float f32x4;
typedef __attribute__((ext_vector_type(4))) unsigned uint4v;

#define MFMA16(a, b, c) __builtin_amdgcn_mfma_f32_16x16x32_bf16((a), (b), (c), 0, 0, 0)

__device__ __forceinline__ unsigned pk2(float lo, float hi) {
  unsigned r;
  asm("v_cvt_pk_bf16_f32 %0, %1, %2" : "=v"(r) : "v"(lo), "v"(hi));
  return r;
}

__device__ __forceinline__ float fexp2(float x) {
  float y; asm("v_exp_f32 %0, %1" : "=v"(y) : "v"(x)); return y;
}

__device__ __forceinline__ f32x4 zero4() {
  return (f32x4){0.0f, 0.0f, 0.0f, 0.0f};
}

constexpr int S_ = 1024, D = 128;
constexpr int QSTR = 32 * 128;  // query/out row stride (floats)
constexpr int KSTR = 8 * 128;   // key/value row stride (floats)
// log2(e)/sqrt(128): scores computed directly in log2 domain
constexpr float QSCL = 0.12751741f;

// grid = 512, block = 1024 (16 waves). bid -> (hkv, b, qt64) heavy-first —
// IDENTICAL grid/decode/staging-volume/L3 behavior to the proven R9 kernel.
// R12 change: 16x16 fragments. 16 waves = 4 heads x 4 strips of 16 q-rows
// (block still covers 4 heads x 64 rows). Per-wave state: acc 32 + scores 16
// + qf 16 + staging 16 (1024 threads share the tile) ~= 115 regs -> fits the
// 128 cap -> 4 waves/SIMD (2x TLP; R11 accounting: SIMDs were 88% idle at
// 2 waves). MFMA layouts (m89/m91-verified family): A row=lane&15,
// k=(lane>>4)*8+j; B col=lane&15; D col=lane&15,row=4*(lane>>4)+reg.
// Swapped QK -> lane holds S[kv][q=lane&15]; PV A-frag regroup via 16 shfl +
// 8 half-selects (lane keeps its q). K/V LDS layouts + XOR swizzles as R9.
__global__ __launch_bounds__(1024, 4) void fa_kernel(
    const float* __restrict__ Qg, const float* __restrict__ Kg,
    const float* __restrict__ Vg, float* __restrict__ Og) {
  const int bid  = blockIdx.x;
  const int hkv  = bid & 7;
  const int b    = (bid >> 3) & 3;
  const int qt64 = 15 - (bid >> 5);   // 0..15, heaviest dispatched first

  const int tid  = threadIdx.x;
  const int wid  = tid >> 6;          // 0..15
  const int lane = tid & 63;
  const int q16  = lane & 15;
  const int lg   = lane >> 4;         // 0..3

  const int g     = wid & 3;
  const int strip = wid >> 2;         // 0..3
  const int h     = (hkv << 2) + g;
  const int wq0   = (qt64 << 6) + (strip << 4);
  const int qrow  = wq0 + q16;

  // K: [64 kv][128 bf16] rows of 256B = 16 slots, slot ^= (row&7)
  // V: transposed [128 d][64 bf16] rows of 128B = 8 slots, slot ^= (d&7)
  __shared__ __align__(16) unsigned char Kl0[64 * 256];
  __shared__ __align__(16) unsigned char Vl0[128 * 128];
  __shared__ __align__(16) unsigned char Kl1[64 * 256];
  __shared__ __align__(16) unsigned char Vl1[128 * 128];

  // ---- Q fragments (B operand; pre-scaled into log2 domain) ----
  // qf[c] covers d = 32c + 8*lg + [0..8) for q-row = wq0 + q16.
  bf16x8 qf[4];
  {
    const float* qp = Qg + (size_t)(b * S_ + qrow) * QSTR + h * D;
#pragma unroll
    for (int c = 0; c < 4; ++c) {
      const float4* p4 = (const float4*)(qp + 32 * c + 8 * lg);
      float4 x = p4[0], y = p4[1];
      uint4v w = (uint4v){pk2(x.x * QSCL, x.y * QSCL), pk2(x.z * QSCL, x.w * QSCL),
                          pk2(y.x * QSCL, y.y * QSCL), pk2(y.z * QSCL, y.w * QSCL)};
      qf[c] = __builtin_bit_cast(bf16x8, w);
    }
  }

  // ---- staging maps (1024 threads share one 64-kv tile) ----
  const int kvrow = tid >> 4;            // K: 16 threads per kv row
  const int dbase = (tid & 15) << 3;     // 8 floats each
  const float* kbase = Kg + (size_t)(b * S_) * KSTR + hkv * D;
  const int vd   = tid & 127;            // V: d index 0..127
  const int vkvb = (tid >> 7) << 3;      // kv sub-block 0,8,...,56
  const float* vbase = Vg + (size_t)(b * S_) * KSTR + hkv * D;

  float4 kreg[2];
  float  vreg[8];

  auto ISSUE = [&](int kv0) {
    const float4* kp = (const float4*)(kbase + (size_t)(kv0 + kvrow) * KSTR + dbase);
    kreg[0] = kp[0];
    kreg[1] = kp[1];
    const float* vp = vbase + (size_t)(kv0 + vkvb) * KSTR + vd;
#pragma unroll
    for (int kk = 0; kk < 8; ++kk) vreg[kk] = vp[kk * KSTR];
  };

  auto WRITE = [&](unsigned char* Kl, unsigned char* Vl) {
    uint4v wk = (uint4v){pk2(kreg[0].x, kreg[0].y), pk2(kreg[0].z, kreg[0].w),
                         pk2(kreg[1].x, kreg[1].y), pk2(kreg[1].z, kreg[1].w)};
    *(uint4v*)(Kl + kvrow * 256 + (((tid & 15) ^ (kvrow & 7)) << 4)) = wk;
    uint4v wv = (uint4v){pk2(vreg[0], vreg[1]), pk2(vreg[2], vreg[3]),
                         pk2(vreg[4], vreg[5]), pk2(vreg[6], vreg[7])};
    *(uint4v*)(Vl + vd * 128 + (((tid >> 7) ^ (vd & 7)) << 4)) = wv;
  };

  f32x4 o0 = zero4(), o1 = zero4(), o2 = zero4(), o3 = zero4();
  f32x4 o4 = zero4(), o5 = zero4(), o6 = zero4(), o7 = zero4();
  float m = -1e30f, lsum = 0.0f;

  auto COMPUTE = [&](const unsigned char* Kl, const unsigned char* Vl, int kv0) {
    // ---- swapped QK^T: S^T[kv][q] = K . Q^T; s_kb: kv = kv0+16kb+4lg+reg, q = q16 ----
    f32x4 s0 = zero4(), s1 = zero4(), s2 = zero4(), s3 = zero4();
    __builtin_amdgcn_s_setprio(1);
#pragma unroll
    for (int c = 0; c < 4; ++c) {
      const int so = ((4 * c + lg) ^ (q16 & 7)) << 4;   // (row&7) == (q16&7)
      const unsigned char* Kb = Kl + q16 * 256 + so;
      bf16x8 k0 = *(const bf16x8*)(Kb);
      bf16x8 k1 = *(const bf16x8*)(Kb + 16 * 256);
      bf16x8 k2 = *(const bf16x8*)(Kb + 32 * 256);
      bf16x8 k3 = *(const bf16x8*)(Kb + 48 * 256);
      s0 = MFMA16(k0, qf[c], s0);
      s1 = MFMA16(k1, qf[c], s1);
      s2 = MFMA16(k2, qf[c], s2);
      s3 = MFMA16(k3, qf[c], s3);
    }
    __builtin_amdgcn_s_setprio(0);

    // ---- causal mask (diagonal tile only) ----
    if (kv0 + 63 > wq0) {
      const int kvb_ = kv0 + 4 * lg;
#pragma unroll
      for (int reg = 0; reg < 4; ++reg) {
        if (kvb_ + reg > qrow)      s0[reg] = -1e30f;
        if (kvb_ + 16 + reg > qrow) s1[reg] = -1e30f;
        if (kvb_ + 32 + reg > qrow) s2[reg] = -1e30f;
        if (kvb_ + 48 + reg > qrow) s3[reg] = -1e30f;
      }
    }

    // ---- online softmax (log2 domain), defer-max; per-q = per lane&15 col ----
    float x0 = fmaxf(fmaxf(s0[0], s1[0]), fmaxf(s2[0], s3[0]));
    float x1 = fmaxf(fmaxf(s0[1], s1[1]), fmaxf(s2[1], s3[1]));
    float x2 = fmaxf(fmaxf(s0[2], s1[2]), fmaxf(s2[2], s3[2]));
    float x3 = fmaxf(fmaxf(s0[3], s1[3]), fmaxf(s2[3], s3[3]));
    float mt = fmaxf(fmaxf(x0, x1), fmaxf(x2, x3));
    mt = fmaxf(mt, __shfl_xor(mt, 16));
    mt = fmaxf(mt, __shfl_xor(mt, 32));

    if (__any(mt > m + 6.0f)) {
      const float mn = fmaxf(m, mt);
      const float sc = fexp2(m - mn);
      m = mn;
      lsum *= sc;
      // O rows: q = 4lg + reg -> fetch that q's scale
      const float c0 = __shfl(sc, 4 * lg + 0);
      const float c1 = __shfl(sc, 4 * lg + 1);
      const float c2 = __shfl(sc, 4 * lg + 2);
      const float c3 = __shfl(sc, 4 * lg + 3);
      o0[0] *= c0; o0[1] *= c1; o0[2] *= c2; o0[3] *= c3;
      o1[0] *= c0; o1[1] *= c1; o1[2] *= c2; o1[3] *= c3;
      o2[0] *= c0; o2[1] *= c1; o2[2] *= c2; o2[3] *= c3;
      o3[0] *= c0; o3[1] *= c1; o3[2] *= c2; o3[3] *= c3;
      o4[0] *= c0; o4[1] *= c1; o4[2] *= c2; o4[3] *= c3;
      o5[0] *= c0; o5[1] *= c1; o5[2] *= c2; o5[3] *= c3;
      o6[0] *= c0; o6[1] *= c1; o6[2] *= c2; o6[3] *= c3;
      o7[0] *= c0; o7[1] *= c1; o7[2] *= c2; o7[3] *= c3;
    }

    // ---- P = exp2(S - m), pack pairs: w[kb] = {kv 4lg+0,1 | 4lg+2,3} +16kb ----
    unsigned wA0, wB0, wA1, wB1, wA2, wB2, wA3, wB3;
    {
      float p0 = fexp2(s0[0] - m), p1 = fexp2(s0[1] - m);
      float p2 = fexp2(s0[2] - m), p3 = fexp2(s0[3] - m);
      lsum += (p0 + p1) + (p2 + p3);
      wA0 = pk2(p0, p1); wB0 = pk2(p2, p3);
    }
    {
      float p0 = fexp2(s1[0] - m), p1 = fexp2(s1[1] - m);
      float p2 = fexp2(s1[2] - m), p3 = fexp2(s1[3] - m);
      lsum += (p0 + p1) + (p2 + p3);
      wA1 = pk2(p0, p1); wB1 = pk2(p2, p3);
    }
    {
      float p0 = fexp2(s2[0] - m), p1 = fexp2(s2[1] - m);
      float p2 = fexp2(s2[2] - m), p3 = fexp2(s2[3] - m);
      lsum += (p0 + p1) + (p2 + p3);
      wA2 = pk2(p0, p1); wB2 = pk2(p2, p3);
    }
    {
      float p0 = fexp2(s3[0] - m), p1 = fexp2(s3[1] - m);
      float p2 = fexp2(s3[2] - m), p3 = fexp2(s3[3] - m);
      lsum += (p0 + p1) + (p2 + p3);
      wA3 = pk2(p0, p1); wB3 = pk2(p2, p3);
    }

    // ---- regroup into PV A-frags: lane needs P[q16][kv = 32kvb + 8lg + j].
    // kv 8lg+{0..3} held by lane (q16 + 16*2(lg&1)), +{4..7} by that +16;
    // kb-candidate select by wave-half (kb* = 2kvb + (lane>>5)). ----
    const int src0 = q16 + ((lg & 1) << 5);
    const int src1 = src0 + 16;
    const bool uh = (lane >= 32);
    bf16x8 A0, A1;
    {
      unsigned e0 = __shfl(wA0, src0), f0 = __shfl(wA1, src0);
      unsigned e1 = __shfl(wB0, src0), f1 = __shfl(wB1, src0);
      unsigned e2 = __shfl(wA0, src1), f2 = __shfl(wA1, src1);
      unsigned e3 = __shfl(wB0, src1), f3 = __shfl(wB1, src1);
      uint4v a = (uint4v){uh ? f0 : e0, uh ? f1 : e1, uh ? f2 : e2, uh ? f3 : e3};
      A0 = __builtin_bit_cast(bf16x8, a);
    }
    {
      unsigned e0 = __shfl(wA2, src0), f0 = __shfl(wA3, src0);
      unsigned e1 = __shfl(wB2, src0), f1 = __shfl(wB3, src0);
      unsigned e2 = __shfl(wA2, src1), f2 = __shfl(wA3, src1);
      unsigned e3 = __shfl(wB2, src1), f3 = __shfl(wB3, src1);
      uint4v a = (uint4v){uh ? f0 : e0, uh ? f1 : e1, uh ? f2 : e2, uh ? f3 : e3};
      A1 = __builtin_bit_cast(bf16x8, a);
    }

    // ---- PV: O[q][d] += P . V ; o_db: d = 16db + q16, q = 4lg + reg ----
    __builtin_amdgcn_s_setprio(1);
    const int vso0 = (lg ^ (q16 & 7)) << 4;         // kvb=0: slot = lg
    const int vso1 = ((4 + lg) ^ (q16 & 7)) << 4;   // kvb=1: slot = 4+lg
    const unsigned char* Vb = Vl + q16 * 128;
    {
      bf16x8 v0 = *(const bf16x8*)(Vb + 0 * 2048 + vso0);
      bf16x8 v1 = *(const bf16x8*)(Vb + 0 * 2048 + vso1);
      o0 = MFMA16(A0, v0, o0); o0 = MFMA16(A1, v1, o0);
    }
    {
      bf16x8 v0 = *(const bf16x8*)(Vb + 1 * 2048 + vso0);
      bf16x8 v1 = *(const bf16x8*)(Vb + 1 * 2048 + vso1);
      o1 = MFMA16(A0, v0, o1); o1 = MFMA16(A1, v1, o1);
    }
    {
      bf16x8 v0 = *(const bf16x8*)(Vb + 2 * 2048 + vso0);
      bf16x8 v1 = *(const bf16x8*)(Vb + 2 * 2048 + vso1);
      o2 = MFMA16(A0, v0, o2); o2 = MFMA16(A1, v1, o2);
    }
    {
      bf16x8 v0 = *(const bf16x8*)(Vb + 3 * 2048 + vso0);
      bf16x8 v1 = *(const bf16x8*)(Vb + 3 * 2048 + vso1);
      o3 = MFMA16(A0, v0, o3); o3 = MFMA16(A1, v1, o3);
    }
    {
      bf16x8 v0 = *(const bf16x8*)(Vb + 4 * 2048 + vso0);
      bf16x8 v1 = *(const bf16x8*)(Vb + 4 * 2048 + vso1);
      o4 = MFMA16(A0, v0, o4); o4 = MFMA16(A1, v1, o4);
    }
    {
      bf16x8 v0 = *(const bf16x8*)(Vb + 5 * 2048 + vso0);
      bf16x8 v1 = *(const bf16x8*)(Vb + 5 * 2048 + vso1);
      o5 = MFMA16(A0, v0, o5); o5 = MFMA16(A1, v1, o5);
    }
    {
      bf16x8 v0 = *(const bf16x8*)(Vb + 6 * 2048 + vso0);
      bf16x8 v1 = *(const bf16x8*)(Vb + 6 * 2048 + vso1);
      o6 = MFMA16(A0, v0, o6); o6 = MFMA16(A1, v1, o6);
    }
    {
      bf16x8 v0 = *(const bf16x8*)(Vb + 7 * 2048 + vso0);
      bf16x8 v1 = *(const bf16x8*)(Vb + 7 * 2048 + vso1);
      o7 = MFMA16(A0, v0, o7); o7 = MFMA16(A1, v1, o7);
    }
    __builtin_amdgcn_s_setprio(0);
  };

  const int nt = qt64 + 1;   // number of 64-kv tiles (1..16)

  // Prologue: stage tile 0, launch loads for tile 1.
  ISSUE(0);
  WRITE(Kl0, Vl0);
  if (nt > 1) ISSUE(64);

  unsigned char *Kc = Kl0, *Vc = Vl0, *Kn = Kl1, *Vn = Vl1;
  for (int t = 0; t < nt; ++t) {
    __syncthreads();   // tile t visible; all waves' reads of 'next' buffer done
    if ((strip & 1) == 0) {
      COMPUTE(Kc, Vc, t << 6);
      if (t + 1 < nt) {
        WRITE(Kn, Vn);
        if (t + 2 < nt) ISSUE((t + 2) << 6);
      }
    } else {
      if (t + 1 < nt) {
        WRITE(Kn, Vn);
        if (t + 2 < nt) ISSUE((t + 2) << 6);
      }
      COMPUTE(Kc, Vc, t << 6);
    }
    if (t + 1 < nt) {
      unsigned char* tp;
      tp = Kc; Kc = Kn; Kn = tp;
      tp = Vc; Vc = Vn; Vn = tp;
    }
  }

  // ---- epilogue: column totals (lanes q16, +16, +32, +48) then write ----
  float lt = lsum + __shfl_xor(lsum, 16);
  lt += __shfl_xor(lt, 32);
  const float i0 = 1.0f / __shfl(lt, 4 * lg + 0);
  const float i1 = 1.0f / __shfl(lt, 4 * lg + 1);
  const float i2 = 1.0f / __shfl(lt, 4 * lg + 2);
  const float i3 = 1.0f / __shfl(lt, 4 * lg + 3);
  float* op = Og + (size_t)(b * S_ + wq0 + 4 * lg) * QSTR + h * D + q16;
  op[0 * QSTR +   0] = o0[0] * i0; op[1 * QSTR +   0] = o0[1] * i1;
  op[2 * QSTR +   0] = o0[2] * i2; op[3 * QSTR +   0] = o0[3] * i3;
  op[0 * QSTR +  16] = o1[0] * i0; op[1 * QSTR +  16] = o1[1] * i1;
  op[2 * QSTR +  16] = o1[2] * i2; op[3 * QSTR +  16] = o1[3] * i3;
  op[0 * QSTR +  32] = o2[0] * i0; op[1 * QSTR +  32] = o2[1] * i1;
  op[2 * QSTR +  32] = o2[2] * i2; op[3 * QSTR +  32] = o2[3] * i3;
  op[0 * QSTR +  48] = o3[0] * i0; op[1 * QSTR +  48] = o3[1] * i1;
  op[2 * QSTR +  48] = o3[2] * i2; op[3 * QSTR +  48] = o3[3] * i3;
  op[0 * QSTR +  64] = o4[0] * i0; op[1 * QSTR +  64] = o4[1] * i1;
  op[2 * QSTR +  64] = o4[2] * i2; op[3 * QSTR +  64] = o4[3] * i3;
  op[0 * QSTR +  80] = o5[0] * i0; op[1 * QSTR +  80] = o5[1] * i1;
  op[2 * QSTR +  80] = o5[2] * i2; op[3 * QSTR +  80] = o5[3] * i3;
  op[0 * QSTR +  96] = o6[0] * i0; op[1 * QSTR +  96] = o6[1] * i1;
  op[2 * QSTR +  96] = o6[2] * i2; op[3 * QSTR +  96] = o6[3] * i3;
  op[0 * QSTR + 112] = o7[0] * i0; op[1 * QSTR + 112] = o7[1] * i1;
  op[2 * QSTR + 112] = o7[2] * i2; op[3 * QSTR + 112] = o7[3] * i3;
}

extern "C" void kernel_launch(void* const* d_in, const int* in_sizes, int n_in,
                              void* d_out, int out_size, void* d_ws, size_t ws_size,
                              hipStream_t stream) {
  const float* Q = (const float*)d_in[0];
  const float* K = (const float*)d_in[1];
  const float* V = (const float*)d_in[2];
  float* O = (float*)d_out;
  fa_kernel<<<dim3(512), dim3(1024), 0, stream>>>(Q, K, V, O);
}

// Round 14
// 61.456 us; speedup vs baseline: 1.1208x; 1.1208x over previous
//
#include <hip/hip_runtime.h>

typedef __attribute__((ext_vector_type(8))) short bf16x8;
typedef __attribute__((ext_vector_type(16))) float f32x16;
typedef __attribute__((ext_vector_type(4))) unsigned uint4v;
typedef __attribute__((ext_vector_type(2))) unsigned uint2v;

#define MFMA32(a, b, c) __builtin_amdgcn_mfma_f32_32x32x16_bf16((a), (b), (c), 0, 0, 0)

__device__ __forceinline__ unsigned pk2(float lo, float hi) {
  unsigned r;
  asm("v_cvt_pk_bf16_f32 %0, %1, %2" : "=v"(r) : "v"(lo), "v"(hi));
  return r;
}

__device__ __forceinline__ float fexp2(float x) {
  float y; asm("v_exp_f32 %0, %1" : "=v"(y) : "v"(x)); return y;
}

__device__ __forceinline__ f32x16 zero16() {
  f32x16 z;
#pragma unroll
  for (int i = 0; i < 16; ++i) z[i] = 0.0f;
  return z;
}

constexpr int S_ = 1024, D = 128;
constexpr int QSTR = 32 * 128;  // query/out row stride (floats)
constexpr int KSTR = 8 * 128;   // key/value row stride (floats)
// log2(e)/sqrt(128): scores computed directly in log2 domain
constexpr float QSCL = 0.12751741f;

// ===== R14 = R9 (proven 60.7us) + pack->PV fusion only =====
// grid = 512, block = 512 (8 waves). bid -> (hkv, b, qt64), heavy-first.
// GQA-folded (R4, +30%); dbuf LDS, 1 barrier/tile; wave phase-stagger (R9).
// R13's failure isolated: permlane32_swap(v,v) self-reduce is WRONG — the
// instruction is a two-register in-place half-exchange; with coalesced
// identical operands both outputs become v[lane^32] and the lane's own value
// is lost. Reductions stay on proven __shfl_xor. The KEPT change: pack->PV
// fused per 32-kv half under the single joint max/rescale (mathematically
// identical reordering): PV(t=0,1) MFMAs issue under s1's exps/packs, and
// A-fragment liveness halves (16 -> 8 regs).
// Falsified (do not retry): balance schemes (R5/R6/R7), KVBLK=128 (R8 spill),
// duplicated softmax reductions (R10), 16x16 frags (R12 LDS-pipe bound),
// permlane self-reduce (R13 wrong).
__global__ __launch_bounds__(512, 2) void fa_kernel(
    const float* __restrict__ Qg, const float* __restrict__ Kg,
    const float* __restrict__ Vg, float* __restrict__ Og) {
  const int bid  = blockIdx.x;
  const int hkv  = bid & 7;
  const int b    = (bid >> 3) & 3;
  const int qt64 = 15 - (bid >> 5);   // 0..15, heaviest dispatched first
  const int h4   = hkv << 2;

  const int tid  = threadIdx.x;
  const int wid  = tid >> 6;          // 0..7
  const int lane = tid & 63;
  const int r    = lane & 31;
  const int hi   = lane >> 5;

  const int g     = wid & 3;
  const int strip = wid >> 2;
  const int h     = h4 + g;
  const int wq0   = (qt64 << 6) + (strip << 5);
  const int qrow  = wq0 + r;

  // K: [64 kv][128 bf16] rows of 256B = 16 slots, slot ^= (row&7)
  // V: transposed [128 d][64 bf16] rows of 128B = 8 slots, slot ^= (d&7)
  __shared__ __align__(16) unsigned char Kl0[64 * 256];
  __shared__ __align__(16) unsigned char Vl0[128 * 128];
  __shared__ __align__(16) unsigned char Kl1[64 * 256];
  __shared__ __align__(16) unsigned char Vl1[128 * 128];

  // ---- Q fragments (pre-scaled into log2 domain) ----
  bf16x8 qf[8];
  {
    const float* qp = Qg + (size_t)(b * S_ + qrow) * QSTR + h * D;
#pragma unroll
    for (int c = 0; c < 8; ++c) {
      const float4* p4 = (const float4*)(qp + 16 * c + 8 * hi);
      float4 x = p4[0], y = p4[1];
      uint4v w = (uint4v){pk2(x.x * QSCL, x.y * QSCL), pk2(x.z * QSCL, x.w * QSCL),
                          pk2(y.x * QSCL, y.y * QSCL), pk2(y.z * QSCL, y.w * QSCL)};
      qf[c] = __builtin_bit_cast(bf16x8, w);
    }
  }

  // ---- prefetch registers + stage mapping (512 threads share one tile) ----
  const int kvrow = tid >> 3;            // K: 8 threads per kv row
  const int dbase = (tid & 7) << 4;      // 16 floats each
  const float* kbase = Kg + (size_t)(b * S_) * KSTR + hkv * D;
  const int vd   = tid & 127;            // V: d index 0..127
  const int vkvb = (tid >> 7) << 4;      // kv sub-block 0/16/32/48
  const float* vbase = Vg + (size_t)(b * S_) * KSTR + hkv * D;

  float4 kreg[4];
  float  vreg[16];

  auto ISSUE = [&](int kv0) {
    const float4* kp = (const float4*)(kbase + (size_t)(kv0 + kvrow) * KSTR + dbase);
#pragma unroll
    for (int j = 0; j < 4; ++j) kreg[j] = kp[j];
    const float* vp = vbase + (size_t)(kv0 + vkvb) * KSTR + vd;
#pragma unroll
    for (int kk = 0; kk < 16; ++kk) vreg[kk] = vp[kk * KSTR];
  };

  auto WRITE = [&](unsigned char* Kl, unsigned char* Vl) {
#pragma unroll
    for (int ss = 0; ss < 2; ++ss) {
      float4 x = kreg[2 * ss], y = kreg[2 * ss + 1];
      uint4v w = (uint4v){pk2(x.x, x.y), pk2(x.z, x.w), pk2(y.x, y.y), pk2(y.z, y.w)};
      const int slot = (dbase >> 3) + ss;   // 2*(tid&7)+ss -> 0..15
      *(uint4v*)(Kl + kvrow * 256 + ((slot ^ (kvrow & 7)) << 4)) = w;
    }
#pragma unroll
    for (int ss = 0; ss < 2; ++ss) {
      uint4v w = (uint4v){pk2(vreg[8 * ss + 0], vreg[8 * ss + 1]),
                          pk2(vreg[8 * ss + 2], vreg[8 * ss + 3]),
                          pk2(vreg[8 * ss + 4], vreg[8 * ss + 5]),
                          pk2(vreg[8 * ss + 6], vreg[8 * ss + 7])};
      const int slot = (vkvb >> 3) + ss;    // 2*(tid>>7)+ss -> 0..7
      *(uint4v*)(Vl + vd * 128 + ((slot ^ (vd & 7)) << 4)) = w;
    }
  };

  f32x16 o0 = zero16(), o1 = zero16(), o2 = zero16(), o3 = zero16();
  float m = -1e30f, lsum = 0.0f;

  auto COMPUTE = [&](const unsigned char* Kl, const unsigned char* Vl, int kv0) {
    // ---- swapped QK^T: S^T[kv][q] = K . Q^T ----
    f32x16 s0 = zero16(), s1 = zero16();
    __builtin_amdgcn_s_setprio(1);
#pragma unroll
    for (int c = 0; c < 8; ++c) {
      const int so = (((2 * c + hi) ^ (r & 7)) << 4);
      bf16x8 k0 = *(const bf16x8*)(Kl + r * 256 + so);
      bf16x8 k1 = *(const bf16x8*)(Kl + (32 + r) * 256 + so);
      s0 = MFMA32(k0, qf[c], s0);
      s1 = MFMA32(k1, qf[c], s1);
    }
    __builtin_amdgcn_s_setprio(0);

    // ---- causal mask (diagonal tiles only) ----
    if (kv0 + 63 > wq0) {
#pragma unroll
      for (int rr = 0; rr < 16; ++rr) {
        const int R = (rr & 3) + ((rr >> 2) << 3) + (hi << 2);
        if (kv0 + R > qrow)      s0[rr] = -1e30f;
        if (kv0 + 32 + R > qrow) s1[rr] = -1e30f;
      }
    }

    // ---- online softmax (log2 domain), defer-max; tree-reduced max ----
    float mx[8];
#pragma unroll
    for (int rr = 0; rr < 8; ++rr)
      mx[rr] = fmaxf(fmaxf(s0[rr], s0[rr + 8]), fmaxf(s1[rr], s1[rr + 8]));
#pragma unroll
    for (int rr = 0; rr < 4; ++rr) mx[rr] = fmaxf(mx[rr], mx[rr + 4]);
    float mt = fmaxf(fmaxf(mx[0], mx[1]), fmaxf(mx[2], mx[3]));
    mt = fmaxf(mt, __shfl_xor(mt, 32));

    if (__any(mt > m + 6.0f)) {
      const float mn = fmaxf(m, mt);
      const float sc = fexp2(m - mn);
      m = mn;
      lsum *= sc;
#pragma unroll
      for (int rr = 0; rr < 16; ++rr) {
        const float srow = __shfl(sc, (rr & 3) + ((rr >> 2) << 3) + (hi << 2));
        o0[rr] *= srow; o1[rr] *= srow; o2[rr] *= srow; o3[rr] *= srow;
      }
    }

    // ---- half 0: P0 = exp2(s0 - m) -> A-frags -> PV(t=0,1). Fused so
    //      PV-s0 MFMAs issue under s1's exps; A-frags stay transient. ----
    {
      float p[16];
#pragma unroll
      for (int rr = 0; rr < 16; ++rr) p[rr] = fexp2(s0[rr] - m);
      float pa = 0.0f, pb = 0.0f, pc = 0.0f, pd = 0.0f;
#pragma unroll
      for (int rr = 0; rr < 4; ++rr) {
        pa += p[4 * rr + 0]; pb += p[4 * rr + 1];
        pc += p[4 * rr + 2]; pd += p[4 * rr + 3];
      }
      lsum += (pa + pb) + (pc + pd);
      unsigned d0 = pk2(p[0], p[1]),   d1 = pk2(p[2], p[3]);
      unsigned d2 = pk2(p[4], p[5]),   d3 = pk2(p[6], p[7]);
      unsigned d4 = pk2(p[8], p[9]),   d5 = pk2(p[10], p[11]);
      unsigned d6 = pk2(p[12], p[13]), d7 = pk2(p[14], p[15]);
      uint2v w02 = __builtin_amdgcn_permlane32_swap(d0, d2, false, false);
      uint2v w13 = __builtin_amdgcn_permlane32_swap(d1, d3, false, false);
      uint2v w46 = __builtin_amdgcn_permlane32_swap(d4, d6, false, false);
      uint2v w57 = __builtin_amdgcn_permlane32_swap(d5, d7, false, false);
      bf16x8 Aa = __builtin_bit_cast(bf16x8, (uint4v){w02[0], w13[0], w02[1], w13[1]});
      bf16x8 Ab = __builtin_bit_cast(bf16x8, (uint4v){w46[0], w57[0], w46[1], w57[1]});
      __builtin_amdgcn_s_setprio(1);
#pragma unroll
      for (int t = 0; t < 2; ++t) {
        const bf16x8 pf = (t == 0) ? Aa : Ab;
        const int so = (((2 * t + hi) ^ (r & 7)) << 4);
        bf16x8 v0 = *(const bf16x8*)(Vl + r * 128 + so);
        bf16x8 v1 = *(const bf16x8*)(Vl + (32 + r) * 128 + so);
        bf16x8 v2 = *(const bf16x8*)(Vl + (64 + r) * 128 + so);
        bf16x8 v3 = *(const bf16x8*)(Vl + (96 + r) * 128 + so);
        o0 = MFMA32(pf, v0, o0);
        o1 = MFMA32(pf, v1, o1);
        o2 = MFMA32(pf, v2, o2);
        o3 = MFMA32(pf, v3, o3);
      }
      __builtin_amdgcn_s_setprio(0);
    }

    // ---- half 1: P1 = exp2(s1 - m) -> A-frags -> PV(t=2,3) ----
    {
      float p[16];
#pragma unroll
      for (int rr = 0; rr < 16; ++rr) p[rr] = fexp2(s1[rr] - m);
      float pa = 0.0f, pb = 0.0f, pc = 0.0f, pd = 0.0f;
#pragma unroll
      for (int rr = 0; rr < 4; ++rr) {
        pa += p[4 * rr + 0]; pb += p[4 * rr + 1];
        pc += p[4 * rr + 2]; pd += p[4 * rr + 3];
      }
      lsum += (pa + pb) + (pc + pd);
      unsigned d0 = pk2(p[0], p[1]),   d1 = pk2(p[2], p[3]);
      unsigned d2 = pk2(p[4], p[5]),   d3 = pk2(p[6], p[7]);
      unsigned d4 = pk2(p[8], p[9]),   d5 = pk2(p[10], p[11]);
      unsigned d6 = pk2(p[12], p[13]), d7 = pk2(p[14], p[15]);
      uint2v w02 = __builtin_amdgcn_permlane32_swap(d0, d2, false, false);
      uint2v w13 = __builtin_amdgcn_permlane32_swap(d1, d3, false, false);
      uint2v w46 = __builtin_amdgcn_permlane32_swap(d4, d6, false, false);
      uint2v w57 = __builtin_amdgcn_permlane32_swap(d5, d7, false, false);
      bf16x8 Aa = __builtin_bit_cast(bf16x8, (uint4v){w02[0], w13[0], w02[1], w13[1]});
      bf16x8 Ab = __builtin_bit_cast(bf16x8, (uint4v){w46[0], w57[0], w46[1], w57[1]});
      __builtin_amdgcn_s_setprio(1);
#pragma unroll
      for (int t = 2; t < 4; ++t) {
        const bf16x8 pf = (t == 2) ? Aa : Ab;
        const int so = (((2 * t + hi) ^ (r & 7)) << 4);
        bf16x8 v0 = *(const bf16x8*)(Vl + r * 128 + so);
        bf16x8 v1 = *(const bf16x8*)(Vl + (32 + r) * 128 + so);
        bf16x8 v2 = *(const bf16x8*)(Vl + (64 + r) * 128 + so);
        bf16x8 v3 = *(const bf16x8*)(Vl + (96 + r) * 128 + so);
        o0 = MFMA32(pf, v0, o0);
        o1 = MFMA32(pf, v1, o1);
        o2 = MFMA32(pf, v2, o2);
        o3 = MFMA32(pf, v3, o3);
      }
      __builtin_amdgcn_s_setprio(0);
    }
  };

  const int nt = qt64 + 1;   // number of 64-kv tiles (1..16)

  // Prologue: stage tile 0, launch loads for tile 1.
  ISSUE(0);
  WRITE(Kl0, Vl0);
  if (nt > 1) ISSUE(64);

  unsigned char *Kc = Kl0, *Vc = Vl0, *Kn = Kl1, *Vn = Vl1;
  for (int t = 0; t < nt; ++t) {
    __syncthreads();   // tile t visible; ALL waves' reads of 'next' buffer done
    if (wid < 4) {
      // compute-first half: MFMA burst while sibling wave does VALU/VMEM
      COMPUTE(Kc, Vc, t << 6);
      if (t + 1 < nt) {
        WRITE(Kn, Vn);
        if (t + 2 < nt) ISSUE((t + 2) << 6);
      }
    } else {
      // stage-first half (sibling on same SIMD is in its MFMA phase)
      if (t + 1 < nt) {
        WRITE(Kn, Vn);
        if (t + 2 < nt) ISSUE((t + 2) << 6);
      }
      COMPUTE(Kc, Vc, t << 6);
    }
    if (t + 1 < nt) {
      unsigned char* tp;
      tp = Kc; Kc = Kn; Kn = tp;
      tp = Vc; Vc = Vn; Vn = tp;
    }
  }

  // ---- epilogue ----
  float lt = lsum + __shfl_xor(lsum, 32);
#pragma unroll
  for (int rr = 0; rr < 16; ++rr) {
    const int R = (rr & 3) + ((rr >> 2) << 3) + (hi << 2);
    const float li = __shfl(lt, R);
    const float inv = 1.0f / li;
    float* op = Og + (size_t)(b * S_ + wq0 + R) * QSTR + h * D + r;
    op[0]  = o0[rr] * inv;
    op[32] = o1[rr] * inv;
    op[64] = o2[rr] * inv;
    op[96] = o3[rr] * inv;
  }
}

extern "C" void kernel_launch(void* const* d_in, const int* in_sizes, int n_in,
                              void* d_out, int out_size, void* d_ws, size_t ws_size,
                              hipStream_t stream) {
  const float* Q = (const float*)d_in[0];
  const float* K = (const float*)d_in[1];
  const float* V = (const float*)d_in[2];
  float* O = (float*)d_out;
  fa_kernel<<<dim3(512), dim3(512), 0, stream>>>(Q, K, V, O);
}